// Round 1
// baseline (648.236 us; speedup 1.0000x reference)
//
#include <hip/hip_runtime.h>
#include <cstdio>
#include <cstddef>

// Problem constants: B=4, L=1024 -> ROWS=4096; m=64 ctx tokens; Dc=256; Dq=inner=512; H=8; DH=64.
// Algebraic restructuring (exact):
//   scores[r,h,m] = sum_c ctx[r,m,c] * Qk[r,h,c],   Qk[r,h,c] = scale * sum_d Q[r,hd] Wk[c,hd]
//   out_inner[r,hd] = sum_c CA[r,h,c] * Wv[c,hd],   CA[r,h,c] = sum_m attn[r,h,m] ctx[r,m,c]
// -> avoids the 137 GFLOP K/V projections entirely (8.6 GFLOP total, ctx read ~once).

#define NROWS 4096

// K0: WkT[i*256 + c] = Wk[c*512 + i]   (i = h*64+d)
__global__ __launch_bounds__(256) void k_transpose(const float* __restrict__ Wk,
                                                   float* __restrict__ WkT) {
  int idx = blockIdx.x * 256 + threadIdx.x;   // 0..131071
  int i = idx >> 8, c = idx & 255;
  WkT[idx] = Wk[c * 512 + i];
}

// K1/K5: Y[r,n] = sum_k X[r,k] * W[k*512+n] (+bias). 8 rows/block, 512 blocks.
// Safe for X==Y: all X reads happen before the barrier, all Y writes after, rows disjoint per block.
__global__ __launch_bounds__(256) void k_gemm512(const float* X, const float* __restrict__ W,
                                                 const float* __restrict__ bias, float* Y) {
  __shared__ float xs[8 * 512];
  int t = threadIdx.x;
  size_t r0 = (size_t)blockIdx.x * 8;
  const float4* x4 = (const float4*)(X + r0 * 512);
  float4* s4 = (float4*)xs;
#pragma unroll
  for (int i = 0; i < 4; ++i) s4[t + i * 256] = x4[t + i * 256];
  __syncthreads();
  int n0 = t, n1 = t + 256;
  float acc0[8] = {}, acc1[8] = {};
#pragma unroll 4
  for (int k = 0; k < 512; ++k) {
    float w0 = W[k * 512 + n0];
    float w1 = W[k * 512 + n1];
#pragma unroll
    for (int rr = 0; rr < 8; ++rr) {
      float xv = xs[rr * 512 + k];              // wave-uniform -> LDS broadcast
      acc0[rr] = fmaf(xv, w0, acc0[rr]);
      acc1[rr] = fmaf(xv, w1, acc1[rr]);
    }
  }
  float b0 = bias ? bias[n0] : 0.f;
  float b1 = bias ? bias[n1] : 0.f;
#pragma unroll
  for (int rr = 0; rr < 8; ++rr) {
    Y[(r0 + rr) * 512 + n0] = acc0[rr] + b0;
    Y[(r0 + rr) * 512 + n1] = acc1[rr] + b1;
  }
}

// K2: Qk[r, h*256+c] = scale * sum_d Q[r, h*64+d] * WkT[(h*64+d)*256 + c]. 8 rows/block.
__global__ __launch_bounds__(256) void k_qproj_k(const float* __restrict__ Q,
                                                 const float* __restrict__ WkT,
                                                 float* __restrict__ Qk) {
  __shared__ float qs[8 * 512];
  int t = threadIdx.x;
  size_t r0 = (size_t)blockIdx.x * 8;
  const float4* q4 = (const float4*)(Q + r0 * 512);
  float4* s4 = (float4*)qs;
#pragma unroll
  for (int i = 0; i < 4; ++i) s4[t + i * 256] = q4[t + i * 256];
  __syncthreads();
  float acc[8][8] = {};   // [row][head]
  int c = t;
  for (int d = 0; d < 64; ++d) {
    float w[8];
#pragma unroll
    for (int h = 0; h < 8; ++h) w[h] = WkT[(h * 64 + d) * 256 + c];   // coalesced over c
#pragma unroll
    for (int rr = 0; rr < 8; ++rr)
#pragma unroll
      for (int h = 0; h < 8; ++h)
        acc[rr][h] = fmaf(qs[rr * 512 + h * 64 + d], w[h], acc[rr][h]);
  }
#pragma unroll
  for (int rr = 0; rr < 8; ++rr)
#pragma unroll
    for (int h = 0; h < 8; ++h)
      Qk[(r0 + rr) * 2048 + h * 256 + c] = acc[rr][h] * 0.125f;   // scale = 1/sqrt(64)
}

// K3: per-row fused attention. One block per (b,l) row.
// LDS: 32KB ctx chunk (skewed +m to kill bank conflicts) + 8KB Qk + 2KB scores -> ~43.5KB, 3 blocks/CU.
__global__ __launch_bounds__(256) void k_attn(const float* __restrict__ ctx,
                                              const float* __restrict__ Qk,
                                              const float* __restrict__ bias,
                                              const int* __restrict__ mask,
                                              float* __restrict__ CA) {
  __shared__ float ctxs[64 * 128];   // one 128-wide c-chunk of the 64x256 ctx tile, skewed
  __shared__ float qks[2048];
  __shared__ float sc[512];          // [h*64+m]
  __shared__ float bs[64];
  __shared__ int   ms[64];
  int t = threadIdx.x;
  int r = blockIdx.x;
  const float* ctxr = ctx + (size_t)r * 16384;   // 64 x 256

  const float4* q4 = (const float4*)(Qk + (size_t)r * 2048);
  ((float4*)qks)[t]       = q4[t];
  ((float4*)qks)[t + 256] = q4[t + 256];
  if (t < 64) { bs[t] = bias[(size_t)r * 64 + t]; ms[t] = mask[(size_t)r * 64 + t]; }

  int m_ = t & 63;          // lane -> ctx token
  int h0 = t >> 6;          // wave -> heads {h0, h0+4}
  float s0 = 0.f, s1 = 0.f;
  for (int k = 0; k < 2; ++k) {
    __syncthreads();        // (k=0: covers qks/bs/ms too; k=1: protects chunk reuse)
#pragma unroll
    for (int i = 0; i < 8; ++i) {
      int l = t + i * 256;            // float4 index in chunk, 0..2047
      int m = l >> 5, c4 = l & 31;    // 32 float4 per row
      float4 v = ((const float4*)(ctxr + m * 256 + k * 128))[c4];
      int cl = c4 * 4;
      ctxs[m * 128 + ((cl + 0 + m) & 127)] = v.x;   // skew-by-m storage
      ctxs[m * 128 + ((cl + 1 + m) & 127)] = v.y;
      ctxs[m * 128 + ((cl + 2 + m) & 127)] = v.z;
      ctxs[m * 128 + ((cl + 3 + m) & 127)] = v.w;
    }
    __syncthreads();
    const float* q0 = qks + h0 * 256 + k * 128;
    const float* q1 = q0 + 1024;      // head h0+4
    const float* cp = ctxs + m_ * 128;
#pragma unroll 4
    for (int cc = 0; cc < 128; ++cc) {
      float cv = cp[(cc + m_) & 127]; // logical element (m_, k*128+cc); banks 2-way -> free
      s0 = fmaf(cv, q0[cc], s0);
      s1 = fmaf(cv, q1[cc], s1);
    }
  }
  bool valid = ms[m_] != 0;
  float b = bs[m_];
  sc[h0 * 64 + m_]       = valid ? s0 + b : -INFINITY;
  sc[(h0 + 4) * 64 + m_] = valid ? s1 + b : -INFINITY;
  __syncthreads();
  if (t < 8) {                       // per-head softmax over m=64 (tiny, serial is fine)
    float mx = -INFINITY;
    for (int m = 0; m < 64; ++m) mx = fmaxf(mx, sc[t * 64 + m]);
    float sum = 0.f;
    for (int m = 0; m < 64; ++m) { float e = expf(sc[t * 64 + m] - mx); sc[t * 64 + m] = e; sum += e; }
    float inv = 1.f / sum;
    for (int m = 0; m < 64; ++m) sc[t * 64 + m] *= inv;
  }
  __syncthreads();
  // CA[h,c] = sum_m attn[h,m] * ctx[m,c]; lane = c -> fully coalesced global re-read (L2-hot)
  float acc[8] = {};
#pragma unroll 4
  for (int m = 0; m < 64; ++m) {
    float cv = ctxr[m * 256 + t];
#pragma unroll
    for (int h = 0; h < 8; ++h) acc[h] = fmaf(sc[h * 64 + m], cv, acc[h]);
  }
#pragma unroll
  for (int h = 0; h < 8; ++h) CA[(size_t)r * 2048 + h * 256 + t] = acc[h];
}

// K4: out_inner[r,n] = sum_c CA[r, (n>>6)*256 + c] * Wv[c*512+n]. 8 rows/block.
__global__ __launch_bounds__(256) void k_outproj_v(const float* __restrict__ CA,
                                                   const float* __restrict__ Wv,
                                                   float* __restrict__ Y) {
  __shared__ float cas[8 * 2048];   // 64KB
  int t = threadIdx.x;
  size_t r0 = (size_t)blockIdx.x * 8;
  const float4* c4 = (const float4*)(CA + r0 * 2048);
  float4* s4 = (float4*)cas;
#pragma unroll
  for (int i = 0; i < 16; ++i) s4[t + i * 256] = c4[t + i * 256];
  __syncthreads();
  int n0 = t, n1 = t + 256;
  int h0 = n0 >> 6, h1 = n1 >> 6;
  float acc0[8] = {}, acc1[8] = {};
#pragma unroll 4
  for (int c = 0; c < 256; ++c) {
    float w0 = Wv[c * 512 + n0];
    float w1 = Wv[c * 512 + n1];
#pragma unroll
    for (int rr = 0; rr < 8; ++rr) {
      acc0[rr] = fmaf(cas[rr * 2048 + h0 * 256 + c], w0, acc0[rr]);
      acc1[rr] = fmaf(cas[rr * 2048 + h1 * 256 + c], w1, acc1[rr]);
    }
  }
#pragma unroll
  for (int rr = 0; rr < 8; ++rr) {
    Y[(r0 + rr) * 512 + n0] = acc0[rr];
    Y[(r0 + rr) * 512 + n1] = acc1[rr];
  }
}

extern "C" void kernel_launch(void* const* d_in, const int* in_sizes, int n_in,
                              void* d_out, int out_size, void* d_ws, size_t ws_size,
                              hipStream_t stream) {
  const float* x    = (const float*)d_in[0];
  const float* ctx  = (const float*)d_in[1];
  const int*   mask = (const int*)d_in[2];
  const float* bias = (const float*)d_in[3];
  const float* Wq   = (const float*)d_in[4];
  const float* Wk   = (const float*)d_in[5];
  const float* Wv   = (const float*)d_in[6];
  const float* Wo   = (const float*)d_in[7];
  const float* bo   = (const float*)d_in[8];
  float* out = (float*)d_out;

  float* ws  = (float*)d_ws;
  float* WkT = ws;                       // 131072 floats (0.5 MB)
  float* Qk  = ws + 131072;              // 4096*2048 floats (32 MB)
  float* CA  = Qk + (size_t)NROWS * 2048;// 4096*2048 floats (32 MB)
  size_t need = (size_t)(131072 + 2 * NROWS * 2048) * 4;
  if (ws_size < need)
    fprintf(stderr, "[CrossAttentionEinsum] WARNING ws_size=%zu < need=%zu\n", ws_size, need);

  // Q lives in d_out (dead after K2); out_inner lives in d_out (K4 -> K5 in-place).
  hipLaunchKernelGGL(k_transpose, dim3(512),  dim3(256), 0, stream, Wk, WkT);
  hipLaunchKernelGGL(k_gemm512,   dim3(512),  dim3(256), 0, stream, x, Wq, (const float*)nullptr, out);
  hipLaunchKernelGGL(k_qproj_k,   dim3(512),  dim3(256), 0, stream, out, WkT, Qk);
  hipLaunchKernelGGL(k_attn,      dim3(4096), dim3(256), 0, stream, ctx, Qk, bias, mask, CA);
  hipLaunchKernelGGL(k_outproj_v, dim3(512),  dim3(256), 0, stream, CA, Wv, out);
  hipLaunchKernelGGL(k_gemm512,   dim3(512),  dim3(256), 0, stream, out, Wo, bo, out);
}